// Round 6
// baseline (247.193 us; speedup 1.0000x reference)
//
#include <hip/hip_runtime.h>
#include <hip/hip_fp16.h>

#define CELL 128
#define STEPS 20

__device__ __forceinline__ float fast_sigmoid(float x) { return 1.0f / (1.0f + __expf(-x)); }
__device__ __forceinline__ float fast_tanh(float x) {
    return 2.0f / (1.0f + __expf(-2.0f * x)) - 1.0f;   // fp32, ample precision
}

// One 1024-thread workgroup runs the whole 20-step recurrence on one CU.
// Inputs fp32, output fp32 (verified R4). Gate row g's 256-wide concat row
// [W_ih[g] | W_hh[g]] is split across lane pair (2g, 2g+1): even lane holds
// the W_ih half (dots with x), odd lane the W_hh half (dots with h), each as
// 64 __half2 regs (f16). Partner partials combine via __shfl_xor(p,1).
//
// __launch_bounds__ NOTE (R4/R5 evidence): the 2nd arg behaves as CUDA
// min-BLOCKS-per-CU on this toolchain — (512,2) gave VGPR=128, (1024,4) gave
// VGPR=64, both exactly matching the blocks/CU model and both spilling ~100
// dwords/thread to scratch (R5 WRITE_SIZE=400 KB vs 480 B of output).
// Single-arg form => no occupancy target => full 128-VGPR structural cap.
extern "C" __global__ void __launch_bounds__(1024)
nas_policy_kernel(const int* __restrict__ net,
                  const float* __restrict__ emb_start,   // [1][128]
                  const float* __restrict__ emb_keys,    // [4][6][128]
                  const float* __restrict__ fc_W,        // [4][6][128]
                  const float* __restrict__ fc_b,        // [4][6]
                  const float* __restrict__ W_ih,        // [512][128]
                  const float* __restrict__ W_hh,        // [512][128]
                  const float* __restrict__ b_ih,        // [512]
                  const float* __restrict__ b_hh,        // [512]
                  float* __restrict__ out)               // [20][1][6] fp32
{
    const int t0   = threadIdx.x;    // 0..1023
    const int g    = t0 >> 1;        // gate row 0..511
    const int half = t0 & 1;         // 0: W_ih half (x), 1: W_hh half (h)

    __shared__ __align__(16) float xh[2 * CELL];   // [0..127]=x, [128..255]=h
    __shared__ float gates[4 * CELL];
    __shared__ float logits[8];
    __shared__ float s_embk[24 * CELL];            // emb_keys staged fp32
    __shared__ float s_fcW[24 * CELL];             // fc_W staged fp32
    __shared__ float s_fcb[24];
    __shared__ int   s_net[STEPS];

    // ---- pack this thread's 128 weights into 64 half2 regs (f16) ----
    __half2 wreg[64];
    {
        const float4* s4 = (const float4*)((half ? W_hh : W_ih) + (size_t)g * CELL);
#pragma unroll 8
        for (int q = 0; q < 32; ++q) {
            float4 a = s4[q];
            wreg[2 * q]     = __floats2half2_rn(a.x, a.y);
            wreg[2 * q + 1] = __floats2half2_rn(a.z, a.w);
        }
    }
    const float bias = b_ih[g] + b_hh[g];   // fp32, used by even lane only

    // ---- stage small tensors to LDS; init x, h, c ----
    for (int i = t0; i < 24 * CELL; i += 1024) { s_embk[i] = emb_keys[i]; s_fcW[i] = fc_W[i]; }
    if (t0 < 24)    s_fcb[t0] = fc_b[t0];
    if (t0 < STEPS) s_net[t0] = net[t0];
    if (t0 < CELL)  { xh[t0] = emb_start[t0]; xh[CELL + t0] = 0.0f; }
    float c = 0.0f;

    const int wv    = t0 >> 6;       // wave 0..15
    const int lane  = t0 & 63;
    const int xbase = half * 32;     // even lanes read x (float4 0..31), odd read h (32..63)

    for (int t = 0; t < STEPS; ++t) {
        __syncthreads();   // A: xh (and init staging) ready; prev logits consumed

        // ---- half-row dot: p = w[0..127] . xh[half*128 .. +128] ----
        // unroll 8: caps live x-temps at 8 float4 (32 VGPRs) per chunk so the
        // total live set (~64 wreg + 32 x + misc) stays under the 128 cap.
        const float4* x4 = (const float4*)xh;
        float a0 = 0.f, a1 = 0.f, a2 = 0.f, a3 = 0.f;
#pragma unroll 8
        for (int q = 0; q < 32; ++q) {
            float4 u = x4[xbase + q];
            __half2 w0 = wreg[2 * q], w1 = wreg[2 * q + 1];
            a0 = fmaf(__low2float(w0),  u.x, a0);   // v_fma_mix candidates
            a1 = fmaf(__high2float(w0), u.y, a1);
            a2 = fmaf(__low2float(w1),  u.z, a2);
            a3 = fmaf(__high2float(w1), u.w, a3);
        }
        float p = (a0 + a1) + (a2 + a3);
        p += __shfl_xor(p, 1);                      // combine x-half + h-half
        if (half == 0) gates[g] = bias + p;

        __syncthreads();   // B: gates ready

        // ---- LSTM elementwise (threads 0..127) + stage next-step x ----
        if (t0 < CELL) {
            float ig = fast_sigmoid(gates[t0]);
            float fg = fast_sigmoid(gates[CELL + t0]);
            float gg = fast_tanh   (gates[2 * CELL + t0]);
            float og = fast_sigmoid(gates[3 * CELL + t0]);
            c = fg * c + ig * gg;
            float h = og * fast_tanh(c);
            xh[CELL + t0] = h;
            xh[t0] = s_embk[(((t & 3) * 6) + s_net[t]) * CELL + t0];  // next x
        }

        __syncthreads();   // C: h ready

        // ---- head logits: wave r (r<6) computes h . fc_W[t%4][r] ----
        if (wv < 6) {
            const float* Wr = s_fcW + (((t & 3) * 6) + wv) * CELL;
            float p2 = xh[CELL + lane]      * Wr[lane]
                     + xh[CELL + 64 + lane] * Wr[64 + lane];
#pragma unroll
            for (int off = 32; off >= 1; off >>= 1) p2 += __shfl_down(p2, off);
            if (lane == 0) logits[wv] = p2 + s_fcb[(t & 3) * 6 + wv];
        }

        __syncthreads();   // D: logits ready

        // ---- softmax over 6 + fp32 output (threads 0..5, redundant) ----
        if (t0 < 6) {
            float l0 = logits[0], l1 = logits[1], l2 = logits[2];
            float l3 = logits[3], l4 = logits[4], l5 = logits[5];
            float m = fmaxf(fmaxf(fmaxf(l0, l1), fmaxf(l2, l3)), fmaxf(l4, l5));
            float e0 = __expf(l0 - m), e1 = __expf(l1 - m), e2 = __expf(l2 - m);
            float e3 = __expf(l3 - m), e4 = __expf(l4 - m), e5 = __expf(l5 - m);
            float s = ((e0 + e1) + (e2 + e3)) + (e4 + e5);
            float mine = (t0 == 0) ? e0 : (t0 == 1) ? e1 : (t0 == 2) ? e2
                       : (t0 == 3) ? e3 : (t0 == 4) ? e4 : e5;
            out[t * 6 + t0] = mine / s;
        }
    }
}

extern "C" void kernel_launch(void* const* d_in, const int* in_sizes, int n_in,
                              void* d_out, int out_size, void* d_ws, size_t ws_size,
                              hipStream_t stream) {
    (void)in_sizes; (void)n_in; (void)out_size; (void)d_ws; (void)ws_size;
    const int*   net       = (const int*)d_in[0];
    // d_in[1] = reward, unused in forward
    const float* emb_start = (const float*)d_in[2];
    const float* emb_keys  = (const float*)d_in[3];
    const float* fc_W      = (const float*)d_in[4];
    const float* fc_b      = (const float*)d_in[5];
    const float* W_ih      = (const float*)d_in[6];
    const float* W_hh      = (const float*)d_in[7];
    const float* b_ih      = (const float*)d_in[8];
    const float* b_hh      = (const float*)d_in[9];
    float*       out       = (float*)d_out;

    hipLaunchKernelGGL(nas_policy_kernel, dim3(1), dim3(1024), 0, stream,
                       net, emb_start, emb_keys, fc_W, fc_b,
                       W_ih, W_hh, b_ih, b_hh, out);
}

// Round 7
// 125.330 us; speedup vs baseline: 1.9723x; 1.9723x over previous
//
#include <hip/hip_runtime.h>
#include <hip/hip_fp16.h>

#define CELL 128
#define STEPS 20

typedef _Float16 half2_t __attribute__((ext_vector_type(2)));

__device__ __forceinline__ float fdot2(half2_t a, half2_t b, float c) {
#if __has_builtin(__builtin_amdgcn_fdot2)
    return __builtin_amdgcn_fdot2(a, b, c, false);   // v_dot2_f32_f16: f32 += a0*b0 + a1*b1
#else
    return fmaf((float)a[0], (float)b[0], fmaf((float)a[1], (float)b[1], c));
#endif
}
__device__ __forceinline__ unsigned packf2(float x, float y) {
    half2_t h = { (_Float16)x, (_Float16)y };
    return __builtin_bit_cast(unsigned, h);
}
__device__ __forceinline__ half2_t as_h2(unsigned u) { return __builtin_bit_cast(half2_t, u); }

__device__ __forceinline__ float fast_sigmoid(float x) { return 1.0f / (1.0f + __expf(-x)); }
__device__ __forceinline__ float fast_tanh(float x) {
    return 2.0f / (1.0f + __expf(-2.0f * x)) - 1.0f;
}

// One 1024-thread workgroup runs the whole 20-step recurrence on one CU.
// Gate row g's 256-wide concat row [W_ih[g] | W_hh[g]] is split across lane
// pair (2g, 2g+1): even lane dots W_ih half with x, odd lane W_hh half with h.
// Weights live in 64 half2 VGPRs/thread; x,h live in LDS as packed half2;
// accumulation is fp32 via v_dot2_f32_f16. Partner partials: __shfl_xor(p,1).
//
// HARD-LEARNED (R4-R6 counters):
//  * 2nd __launch_bounds__ arg acts as min-BLOCKS/CU here: (512,2)->128 VGPR
//    cap, (1024,4)->64 cap, both spilled. Single-arg => structural 128 cap.
//  * Local arrays need compile-time-constant indices (FULL unroll) or they
//    are demoted to scratch: R6's "#pragma unroll 8" put all 64 weight regs
//    in scratch (VGPR_Count=24, WRITE_SIZE=256KB).
extern "C" __global__ void __launch_bounds__(1024)
nas_policy_kernel(const int* __restrict__ net,
                  const float* __restrict__ emb_start,   // [1][128]
                  const float* __restrict__ emb_keys,    // [4][6][128]
                  const float* __restrict__ fc_W,        // [4][6][128]
                  const float* __restrict__ fc_b,        // [4][6]
                  const float* __restrict__ W_ih,        // [512][128]
                  const float* __restrict__ W_hh,        // [512][128]
                  const float* __restrict__ b_ih,        // [512]
                  const float* __restrict__ b_hh,        // [512]
                  float* __restrict__ out)               // [20][1][6] fp32
{
    const int t0   = threadIdx.x;    // 0..1023
    const int g    = t0 >> 1;        // gate row 0..511
    const int half = t0 & 1;         // 0: W_ih half (x), 1: W_hh half (h)

    __shared__ __align__(16) unsigned xh2[2 * 64];     // packed half2: [0..63]=x, [64..127]=h
    __shared__ __align__(16) unsigned s_embk2[24 * 64];// emb_keys packed half2
    __shared__ float h_f32[CELL];                      // fp32 h for the fc head
    __shared__ float gates[4 * CELL];
    __shared__ float s_fcW[24 * CELL];                 // fc head stays fp32
    __shared__ float s_fcb[24];
    __shared__ float logits[8];
    __shared__ int   s_net[STEPS];

    // ---- pack this thread's 128 weights into 64 half2 VGPRs ----
    half2_t wreg[64];
    {
        const float4* s4 = (const float4*)((half ? W_hh : W_ih) + (size_t)g * CELL);
#pragma unroll
        for (int q = 0; q < 32; ++q) {                 // FULL unroll: constant indices
            float4 a = s4[q];
            wreg[2 * q]     = half2_t{ (_Float16)a.x, (_Float16)a.y };
            wreg[2 * q + 1] = half2_t{ (_Float16)a.z, (_Float16)a.w };
        }
    }
    const float bias = b_ih[g] + b_hh[g];

    // ---- stage: emb_keys as half2, fc head as fp32; init x, h ----
    {
        const float2* ek2 = (const float2*)emb_keys;
        for (int i = t0; i < 24 * 64; i += 1024) {
            float2 v = ek2[i];
            s_embk2[i] = packf2(v.x, v.y);
        }
        for (int i = t0; i < 24 * CELL; i += 1024) s_fcW[i] = fc_W[i];
        if (t0 < 24)    s_fcb[t0] = fc_b[t0];
        if (t0 < STEPS) s_net[t0] = net[t0];
        if (t0 < 64) {
            float2 v = ((const float2*)emb_start)[t0];
            xh2[t0]      = packf2(v.x, v.y);           // x0 = emb_start
            xh2[64 + t0] = 0u;                         // h0 = 0 (half2 zero)
        }
    }
    float c = 0.0f;

    const int wv   = t0 >> 6;        // wave 0..15
    const int lane = t0 & 63;

    for (int t = 0; t < STEPS; ++t) {
        __syncthreads();   // A: xh2 (x,h packed) ready; staging/prev logits settled

        // ---- half-row dot: p = w[0..127] . (half? h : x)  [f16 mul, f32 acc] ----
        const uint4* bp = (const uint4*)(xh2 + 64 * half);   // 16 uint4 = 64 half2
        float a0 = 0.f, a1 = 0.f, a2 = 0.f, a3 = 0.f;
#pragma unroll
        for (int q = 0; q < 16; ++q) {                 // FULL unroll: constant indices
            uint4 u = bp[q];
            a0 = fdot2(wreg[4 * q],     as_h2(u.x), a0);
            a1 = fdot2(wreg[4 * q + 1], as_h2(u.y), a1);
            a2 = fdot2(wreg[4 * q + 2], as_h2(u.z), a2);
            a3 = fdot2(wreg[4 * q + 3], as_h2(u.w), a3);
        }
        float p = (a0 + a1) + (a2 + a3);
        p += __shfl_xor(p, 1);                          // x-half + h-half
        if (half == 0) gates[g] = bias + p;

        __syncthreads();   // B: gates ready

        // ---- LSTM elementwise (threads 0..127) ----
        if (t0 < CELL) {
            float ig = fast_sigmoid(gates[t0]);
            float fg = fast_sigmoid(gates[CELL + t0]);
            float gg = fast_tanh   (gates[2 * CELL + t0]);
            float og = fast_sigmoid(gates[3 * CELL + t0]);
            c = fg * c + ig * gg;
            h_f32[t0] = og * fast_tanh(c);
        }

        __syncthreads();   // C: h_f32 ready

        // ---- parallel roles in the C-window ----
        if (wv < 6) {
            // head logits: wave r computes h . fc_W[t%4][r] (fp32)
            const float* Wr = s_fcW + (((t & 3) * 6) + wv) * CELL;
            float p2 = h_f32[lane]      * Wr[lane]
                     + h_f32[64 + lane] * Wr[64 + lane];
#pragma unroll
            for (int off = 32; off >= 1; off >>= 1) p2 += __shfl_down(p2, off);
            if (lane == 0) logits[wv] = p2 + s_fcb[(t & 3) * 6 + wv];
        } else if (wv == 6) {
            // pack h -> half2 for next step's dot
            xh2[64 + lane] = packf2(h_f32[2 * lane], h_f32[2 * lane + 1]);
        } else if (wv == 7) {
            // next-step x: emb_keys[t%4][net[t]] (packed copy)
            xh2[lane] = s_embk2[(((t & 3) * 6) + s_net[t]) * 64 + lane];
        }

        __syncthreads();   // D: logits + next xh2 ready

        // ---- softmax over 6 + fp32 output (threads 0..5, redundant) ----
        if (t0 < 6) {
            float l0 = logits[0], l1 = logits[1], l2 = logits[2];
            float l3 = logits[3], l4 = logits[4], l5 = logits[5];
            float m = fmaxf(fmaxf(fmaxf(l0, l1), fmaxf(l2, l3)), fmaxf(l4, l5));
            float e0 = __expf(l0 - m), e1 = __expf(l1 - m), e2 = __expf(l2 - m);
            float e3 = __expf(l3 - m), e4 = __expf(l4 - m), e5 = __expf(l5 - m);
            float s = ((e0 + e1) + (e2 + e3)) + (e4 + e5);
            float mine = (t0 == 0) ? e0 : (t0 == 1) ? e1 : (t0 == 2) ? e2
                       : (t0 == 3) ? e3 : (t0 == 4) ? e4 : e5;
            out[t * 6 + t0] = mine / s;
        }
    }
}

extern "C" void kernel_launch(void* const* d_in, const int* in_sizes, int n_in,
                              void* d_out, int out_size, void* d_ws, size_t ws_size,
                              hipStream_t stream) {
    (void)in_sizes; (void)n_in; (void)out_size; (void)d_ws; (void)ws_size;
    const int*   net       = (const int*)d_in[0];
    // d_in[1] = reward, unused in forward
    const float* emb_start = (const float*)d_in[2];
    const float* emb_keys  = (const float*)d_in[3];
    const float* fc_W      = (const float*)d_in[4];
    const float* fc_b      = (const float*)d_in[5];
    const float* W_ih      = (const float*)d_in[6];
    const float* W_hh      = (const float*)d_in[7];
    const float* b_ih      = (const float*)d_in[8];
    const float* b_hh      = (const float*)d_in[9];
    float*       out       = (float*)d_out;

    hipLaunchKernelGGL(nas_policy_kernel, dim3(1), dim3(1024), 0, stream,
                       net, emb_start, emb_keys, fc_W, fc_b,
                       W_ih, W_hh, b_ih, b_hh, out);
}

// Round 8
// 121.936 us; speedup vs baseline: 2.0272x; 1.0278x over previous
//
#include <hip/hip_runtime.h>
#include <hip/hip_fp16.h>

#define CELL 128
#define STEPS 20

typedef _Float16 half2_t __attribute__((ext_vector_type(2)));

__device__ __forceinline__ float fdot2(half2_t a, half2_t b, float c) {
#if __has_builtin(__builtin_amdgcn_fdot2)
    return __builtin_amdgcn_fdot2(a, b, c, false);   // v_dot2_f32_f16: f32 += a0*b0 + a1*b1
#else
    return fmaf((float)a[0], (float)b[0], fmaf((float)a[1], (float)b[1], c));
#endif
}
__device__ __forceinline__ unsigned packf2(float x, float y) {
    half2_t h = { (_Float16)x, (_Float16)y };
    return __builtin_bit_cast(unsigned, h);
}
__device__ __forceinline__ half2_t as_h2(unsigned u) { return __builtin_bit_cast(half2_t, u); }

__device__ __forceinline__ float fast_sigmoid(float x) { return 1.0f / (1.0f + __expf(-x)); }
__device__ __forceinline__ float fast_tanh(float x) {
    return 2.0f / (1.0f + __expf(-2.0f * x)) - 1.0f;
}

// One 1024-thread workgroup runs the whole 20-step recurrence on one CU.
// Gate row g's 256-wide concat row [W_ih[g] | W_hh[g]] is split across lane
// pair (2g, 2g+1): even lane dots W_ih half with x, odd lane W_hh half with h.
// Weights: 64 half2 VGPRs/thread. x,h: LDS packed half2. f32 acc via v_dot2.
//
// REGISTER-BUDGET MODEL (R4-R7 counters): VGPR cap = 512/SIMD divided by the
// target waves/EU. Default target (no hint) = 8 -> 64-reg cap (R7: VGPR=64 +
// 12-dword spill, WRITE_SIZE=48KB). launch_bounds 2nd arg maps to blocks/CU:
// (512,2)->128, (1024,4)->64, both observed. Grid=1 => occupancy is worthless;
// pin amdgpu_waves_per_eu(4,4) (our structural residency) -> 128-reg budget.
// Local arrays need FULL unroll (constant indices) or they demote to scratch
// (R6: VGPR=24, 256KB scratch).
extern "C" __global__ void __launch_bounds__(1024)
__attribute__((amdgpu_waves_per_eu(4, 4)))
nas_policy_kernel(const int* __restrict__ net,
                  const float* __restrict__ emb_start,   // [1][128]
                  const float* __restrict__ emb_keys,    // [4][6][128]
                  const float* __restrict__ fc_W,        // [4][6][128]
                  const float* __restrict__ fc_b,        // [4][6]
                  const float* __restrict__ W_ih,        // [512][128]
                  const float* __restrict__ W_hh,        // [512][128]
                  const float* __restrict__ b_ih,        // [512]
                  const float* __restrict__ b_hh,        // [512]
                  float* __restrict__ out)               // [20][1][6] fp32
{
    const int t0   = threadIdx.x;    // 0..1023
    const int g    = t0 >> 1;        // gate row 0..511
    const int half = t0 & 1;         // 0: W_ih half (x), 1: W_hh half (h)

    __shared__ __align__(16) unsigned xh2[2 * 64];      // packed half2: [0..63]=x, [64..127]=h
    __shared__ __align__(16) unsigned s_embk2[24 * 64]; // emb_keys packed half2
    __shared__ float h_f32[CELL];                       // fp32 h for the fc head
    __shared__ float gates[4 * CELL];
    __shared__ float s_fcW[24 * CELL];                  // fc head stays fp32
    __shared__ float s_fcb[24];
    __shared__ float logits[8];
    __shared__ int   s_net[STEPS];

    // ---- pack this thread's 128 weights into 64 half2 VGPRs ----
    half2_t wreg[64];
    {
        const float4* s4 = (const float4*)((half ? W_hh : W_ih) + (size_t)g * CELL);
#pragma unroll
        for (int q = 0; q < 32; ++q) {                  // FULL unroll: constant indices
            float4 a = s4[q];
            wreg[2 * q]     = half2_t{ (_Float16)a.x, (_Float16)a.y };
            wreg[2 * q + 1] = half2_t{ (_Float16)a.z, (_Float16)a.w };
        }
    }
    const float bias = b_ih[g] + b_hh[g];

    // ---- stage: emb_keys as half2, fc head as fp32; init x, h ----
    {
        const float2* ek2 = (const float2*)emb_keys;
        for (int i = t0; i < 24 * 64; i += 1024) {
            float2 v = ek2[i];
            s_embk2[i] = packf2(v.x, v.y);
        }
        for (int i = t0; i < 24 * CELL; i += 1024) s_fcW[i] = fc_W[i];
        if (t0 < 24)    s_fcb[t0] = fc_b[t0];
        if (t0 < STEPS) s_net[t0] = net[t0];
        if (t0 < 64) {
            float2 v = ((const float2*)emb_start)[t0];
            xh2[t0]      = packf2(v.x, v.y);            // x0 = emb_start
            xh2[64 + t0] = 0u;                          // h0 = 0
        }
    }
    float c = 0.0f;

    const int wv   = t0 >> 6;        // wave 0..15
    const int lane = t0 & 63;

    for (int t = 0; t < STEPS; ++t) {
        __syncthreads();   // A: xh2 ready; logits of step t-1 stable until barrier B

        // ---- deferred softmax of step t-1 (threads 0..5; ordered vs t's
        //      logits-overwrite by barrier B) ----
        if (t > 0 && t0 < 6) {
            float l0 = logits[0], l1 = logits[1], l2 = logits[2];
            float l3 = logits[3], l4 = logits[4], l5 = logits[5];
            float m = fmaxf(fmaxf(fmaxf(l0, l1), fmaxf(l2, l3)), fmaxf(l4, l5));
            float e0 = __expf(l0 - m), e1 = __expf(l1 - m), e2 = __expf(l2 - m);
            float e3 = __expf(l3 - m), e4 = __expf(l4 - m), e5 = __expf(l5 - m);
            float s = ((e0 + e1) + (e2 + e3)) + (e4 + e5);
            float mine = (t0 == 0) ? e0 : (t0 == 1) ? e1 : (t0 == 2) ? e2
                       : (t0 == 3) ? e3 : (t0 == 4) ? e4 : e5;
            out[(t - 1) * 6 + t0] = mine / s;
        }

        // ---- half-row dot: p = w[0..127] . (half? h : x)  [f16 mul, f32 acc] ----
        const uint4* bp = (const uint4*)(xh2 + 64 * half);   // 16 uint4 = 64 half2
        float a0 = 0.f, a1 = 0.f, a2 = 0.f, a3 = 0.f;
#pragma unroll
        for (int q = 0; q < 16; ++q) {                  // FULL unroll: constant indices
            uint4 u = bp[q];
            a0 = fdot2(wreg[4 * q],     as_h2(u.x), a0);
            a1 = fdot2(wreg[4 * q + 1], as_h2(u.y), a1);
            a2 = fdot2(wreg[4 * q + 2], as_h2(u.z), a2);
            a3 = fdot2(wreg[4 * q + 3], as_h2(u.w), a3);
        }
        float p = (a0 + a1) + (a2 + a3);
        p += __shfl_xor(p, 1);                          // x-half + h-half
        if (half == 0) gates[g] = bias + p;

        __syncthreads();   // B: gates ready

        // ---- LSTM elementwise (threads 0..127) ----
        if (t0 < CELL) {
            float ig = fast_sigmoid(gates[t0]);
            float fg = fast_sigmoid(gates[CELL + t0]);
            float gg = fast_tanh   (gates[2 * CELL + t0]);
            float og = fast_sigmoid(gates[3 * CELL + t0]);
            c = fg * c + ig * gg;
            h_f32[t0] = og * fast_tanh(c);
        }

        __syncthreads();   // C: h_f32 ready

        // ---- parallel roles in the C-window ----
        if (wv < 6) {
            // head logits: wave r computes h . fc_W[t%4][r] (fp32)
            const float* Wr = s_fcW + (((t & 3) * 6) + wv) * CELL;
            float p2 = h_f32[lane]      * Wr[lane]
                     + h_f32[64 + lane] * Wr[64 + lane];
#pragma unroll
            for (int off = 32; off >= 1; off >>= 1) p2 += __shfl_down(p2, off);
            if (lane == 0) logits[wv] = p2 + s_fcb[(t & 3) * 6 + wv];
        } else if (wv == 6) {
            // pack h -> half2 for next step's dot
            xh2[64 + lane] = packf2(h_f32[2 * lane], h_f32[2 * lane + 1]);
        } else if (wv == 7) {
            // next-step x: emb_keys[t%4][net[t]] (packed copy)
            xh2[lane] = s_embk2[(((t & 3) * 6) + s_net[t]) * 64 + lane];
        }
        // no barrier D: next iteration's barrier A covers logits/xh2;
        // barrier B of t+1 orders the deferred softmax vs their overwrite.
    }

    __syncthreads();       // epilogue: last step's logits
    if (t0 < 6) {
        float l0 = logits[0], l1 = logits[1], l2 = logits[2];
        float l3 = logits[3], l4 = logits[4], l5 = logits[5];
        float m = fmaxf(fmaxf(fmaxf(l0, l1), fmaxf(l2, l3)), fmaxf(l4, l5));
        float e0 = __expf(l0 - m), e1 = __expf(l1 - m), e2 = __expf(l2 - m);
        float e3 = __expf(l3 - m), e4 = __expf(l4 - m), e5 = __expf(l5 - m);
        float s = ((e0 + e1) + (e2 + e3)) + (e4 + e5);
        float mine = (t0 == 0) ? e0 : (t0 == 1) ? e1 : (t0 == 2) ? e2
                   : (t0 == 3) ? e3 : (t0 == 4) ? e4 : e5;
        out[(STEPS - 1) * 6 + t0] = mine / s;
    }
}

extern "C" void kernel_launch(void* const* d_in, const int* in_sizes, int n_in,
                              void* d_out, int out_size, void* d_ws, size_t ws_size,
                              hipStream_t stream) {
    (void)in_sizes; (void)n_in; (void)out_size; (void)d_ws; (void)ws_size;
    const int*   net       = (const int*)d_in[0];
    // d_in[1] = reward, unused in forward
    const float* emb_start = (const float*)d_in[2];
    const float* emb_keys  = (const float*)d_in[3];
    const float* fc_W      = (const float*)d_in[4];
    const float* fc_b      = (const float*)d_in[5];
    const float* W_ih      = (const float*)d_in[6];
    const float* W_hh      = (const float*)d_in[7];
    const float* b_ih      = (const float*)d_in[8];
    const float* b_hh      = (const float*)d_in[9];
    float*       out       = (float*)d_out;

    hipLaunchKernelGGL(nas_policy_kernel, dim3(1), dim3(1024), 0, stream,
                       net, emb_start, emb_keys, fc_W, fc_b,
                       W_ih, W_hh, b_ih, b_hh, out);
}

// Round 9
// 108.810 us; speedup vs baseline: 2.2718x; 1.1206x over previous
//
#include <hip/hip_runtime.h>
#include <hip/hip_fp16.h>

#define CELL 128
#define STEPS 20

typedef _Float16 half8_t __attribute__((ext_vector_type(8)));
typedef float    floatx4 __attribute__((ext_vector_type(4)));

__device__ __forceinline__ unsigned packf2(float x, float y) {
    typedef _Float16 h2 __attribute__((ext_vector_type(2)));
    h2 h = { (_Float16)x, (_Float16)y };
    return __builtin_bit_cast(unsigned, h);
}

__device__ __forceinline__ float fast_sigmoid(float x) { return 1.0f / (1.0f + __expf(-x)); }
__device__ __forceinline__ float fast_tanh(float x) {
    return 2.0f / (1.0f + __expf(-2.0f * x)) - 1.0f;
}

// One 1024-thread workgroup runs the whole 20-step recurrence on one CU.
//
// Gate matvec gates[512] = [x|h](256) . Wcat^T via v_mfma_f32_16x16x32_f16:
// wave w owns gate rows w*32..w*32+31 as two 16-col B-tiles in registers
// (64 dwords/lane). A operand = x|h broadcast to all 16 M-rows: per k-chunk
// every lane reads the same 8-f16 slice (A[m][k]=xh[k] for all m), so one
// 16-lane-broadcast ds_read_b128 per chunk => 8 DS reads/wave/step (vs 16
// in the v_dot2 version) and the dot VALU work moves to the matrix pipe.
//
// REGISTER-BUDGET MODEL (R4-R8 counters): cap = 2048 VGPR/CU / resident
// waves. launch_bounds 2nd arg = min BLOCKS/CU: (512,2)->128, (1024,4)->64,
// default/amdgpu_waves_per_eu(4,4)->64 (attr ignored, R8). (1024,1) => 16
// waves => 128-reg budget. Local arrays need FULL unroll or they demote to
// scratch (R6).
extern "C" __global__ void __launch_bounds__(1024, 1)
nas_policy_kernel(const int* __restrict__ net,
                  const float* __restrict__ emb_start,   // [1][128]
                  const float* __restrict__ emb_keys,    // [4][6][128]
                  const float* __restrict__ fc_W,        // [4][6][128]
                  const float* __restrict__ fc_b,        // [4][6]
                  const float* __restrict__ W_ih,        // [512][128]
                  const float* __restrict__ W_hh,        // [512][128]
                  const float* __restrict__ b_ih,        // [512]
                  const float* __restrict__ b_hh,        // [512]
                  float* __restrict__ out)               // [20][1][6] fp32
{
    const int t0   = threadIdx.x;    // 0..1023
    const int wv   = t0 >> 6;        // wave 0..15
    const int lane = t0 & 63;
    const int quad = lane >> 4;      // 0..3
    const int lcol = lane & 15;      // MFMA col / row-within-tile

    __shared__ __align__(16) unsigned xh2[2 * 64];      // packed half2: [0..63]=x, [64..127]=h
    __shared__ __align__(16) unsigned s_embk2[24 * 64]; // emb_keys packed half2
    __shared__ float h_f32[CELL];                       // fp32 h for the fc head
    __shared__ float gates[4 * CELL];
    __shared__ float s_fcW[24 * CELL];                  // fc head stays fp32
    __shared__ float s_fcb[24];
    __shared__ float logits[8];
    __shared__ int   s_net[STEPS];

    // ---- B-fragments: gate rows r1 = wv*32+lcol (tile 1), r2 = r1+16 (tile 2).
    //      bf{1,2}[kc][j] = Wcat[r][32*kc + quad*8 + j]  (f16, consecutive k) ----
    const int r1 = (wv << 5) + lcol;
    const int r2 = r1 + 16;
    half8_t bf1[8], bf2[8];
#pragma unroll
    for (int kc = 0; kc < 8; ++kc) {                    // FULL unroll: constant indices
        const int k0 = (kc << 5) + (quad << 3);         // 0..255, multiple of 8
        const float* s1 = (k0 < 128) ? (W_ih + r1 * CELL + k0) : (W_hh + r1 * CELL + (k0 - 128));
        const float* s2 = (k0 < 128) ? (W_ih + r2 * CELL + k0) : (W_hh + r2 * CELL + (k0 - 128));
        float4 a = ((const float4*)s1)[0], b = ((const float4*)s1)[1];
        bf1[kc] = half8_t{ (_Float16)a.x, (_Float16)a.y, (_Float16)a.z, (_Float16)a.w,
                           (_Float16)b.x, (_Float16)b.y, (_Float16)b.z, (_Float16)b.w };
        a = ((const float4*)s2)[0]; b = ((const float4*)s2)[1];
        bf2[kc] = half8_t{ (_Float16)a.x, (_Float16)a.y, (_Float16)a.z, (_Float16)a.w,
                           (_Float16)b.x, (_Float16)b.y, (_Float16)b.z, (_Float16)b.w };
    }
    const float bias1 = b_ih[r1] + b_hh[r1];
    const float bias2 = b_ih[r2] + b_hh[r2];

    // ---- stage: emb_keys as half2, fc head as fp32; init x, h ----
    {
        const float2* ek2 = (const float2*)emb_keys;
        for (int i = t0; i < 24 * 64; i += 1024) {
            float2 v = ek2[i];
            s_embk2[i] = packf2(v.x, v.y);
        }
        for (int i = t0; i < 24 * CELL; i += 1024) s_fcW[i] = fc_W[i];
        if (t0 < 24)    s_fcb[t0] = fc_b[t0];
        if (t0 < STEPS) s_net[t0] = net[t0];
        if (t0 < 64) {
            float2 v = ((const float2*)emb_start)[t0];
            xh2[t0]      = packf2(v.x, v.y);            // x0 = emb_start
            xh2[64 + t0] = 0u;                          // h0 = 0
        }
    }
    float c = 0.0f;

    for (int t = 0; t < STEPS; ++t) {
        __syncthreads();   // A: xh2 ready; logits of step t-1 stable until barrier B

        // ---- deferred softmax of step t-1 (threads 0..5) ----
        if (t > 0 && t0 < 6) {
            float l0 = logits[0], l1 = logits[1], l2 = logits[2];
            float l3 = logits[3], l4 = logits[4], l5 = logits[5];
            float m = fmaxf(fmaxf(fmaxf(l0, l1), fmaxf(l2, l3)), fmaxf(l4, l5));
            float e0 = __expf(l0 - m), e1 = __expf(l1 - m), e2 = __expf(l2 - m);
            float e3 = __expf(l3 - m), e4 = __expf(l4 - m), e5 = __expf(l5 - m);
            float s = ((e0 + e1) + (e2 + e3)) + (e4 + e5);
            float mine = (t0 == 0) ? e0 : (t0 == 1) ? e1 : (t0 == 2) ? e2
                       : (t0 == 3) ? e3 : (t0 == 4) ? e4 : e5;
            out[(t - 1) * 6 + t0] = mine / s;
        }

        // ---- gate matvec: two 16-col MFMA tiles, K=256 in 8 chunks ----
        floatx4 acc1 = { 0.f, 0.f, 0.f, 0.f };
        floatx4 acc2 = { 0.f, 0.f, 0.f, 0.f };
        const uint4* xp = (const uint4*)xh2;            // 32 uint4 = 256 f16
#pragma unroll
        for (int kc = 0; kc < 8; ++kc) {
            uint4 u = xp[(kc << 2) + quad];             // 16-lane broadcast read
            half8_t af = __builtin_bit_cast(half8_t, u);   // A[m][k]=xh[k] for all m
            acc1 = __builtin_amdgcn_mfma_f32_16x16x32_f16(af, bf1[kc], acc1, 0, 0, 0);
            acc2 = __builtin_amdgcn_mfma_f32_16x16x32_f16(af, bf2[kc], acc2, 0, 0, 0);
        }
        // C layout: row=(quad*4+reg), col=lcol; all rows identical (A broadcast),
        // so lanes 0..15 (quad=0) hold gate values in acc[0] for col=lane.
        if (lane < 16) {
            gates[(wv << 5) + lane]      = acc1[0] + bias1;
            gates[(wv << 5) + 16 + lane] = acc2[0] + bias2;
        }

        __syncthreads();   // B: gates ready

        // ---- LSTM elementwise (threads 0..127) ----
        if (t0 < CELL) {
            float ig = fast_sigmoid(gates[t0]);
            float fg = fast_sigmoid(gates[CELL + t0]);
            float gg = fast_tanh   (gates[2 * CELL + t0]);
            float og = fast_sigmoid(gates[3 * CELL + t0]);
            c = fg * c + ig * gg;
            h_f32[t0] = og * fast_tanh(c);
        }

        __syncthreads();   // C: h_f32 ready

        // ---- parallel roles in the C-window ----
        if (wv < 6) {
            // head logits: wave r computes h . fc_W[t%4][r] (fp32)
            const float* Wr = s_fcW + (((t & 3) * 6) + wv) * CELL;
            float p2 = h_f32[lane]      * Wr[lane]
                     + h_f32[64 + lane] * Wr[64 + lane];
#pragma unroll
            for (int off = 32; off >= 1; off >>= 1) p2 += __shfl_down(p2, off);
            if (lane == 0) logits[wv] = p2 + s_fcb[(t & 3) * 6 + wv];
        } else if (wv == 6) {
            // pack h -> half2 for next step's MFMA A operand
            xh2[64 + lane] = packf2(h_f32[2 * lane], h_f32[2 * lane + 1]);
        } else if (wv == 7) {
            // next-step x: emb_keys[t%4][net[t]] (packed copy)
            xh2[lane] = s_embk2[(((t & 3) * 6) + s_net[t]) * 64 + lane];
        }
        // no barrier D: next iteration's barrier A covers logits/xh2;
        // barrier B of t+1 orders the deferred softmax vs their overwrite.
    }

    __syncthreads();       // epilogue: last step's logits
    if (t0 < 6) {
        float l0 = logits[0], l1 = logits[1], l2 = logits[2];
        float l3 = logits[3], l4 = logits[4], l5 = logits[5];
        float m = fmaxf(fmaxf(fmaxf(l0, l1), fmaxf(l2, l3)), fmaxf(l4, l5));
        float e0 = __expf(l0 - m), e1 = __expf(l1 - m), e2 = __expf(l2 - m);
        float e3 = __expf(l3 - m), e4 = __expf(l4 - m), e5 = __expf(l5 - m);
        float s = ((e0 + e1) + (e2 + e3)) + (e4 + e5);
        float mine = (t0 == 0) ? e0 : (t0 == 1) ? e1 : (t0 == 2) ? e2
                   : (t0 == 3) ? e3 : (t0 == 4) ? e4 : e5;
        out[(STEPS - 1) * 6 + t0] = mine / s;
    }
}

extern "C" void kernel_launch(void* const* d_in, const int* in_sizes, int n_in,
                              void* d_out, int out_size, void* d_ws, size_t ws_size,
                              hipStream_t stream) {
    (void)in_sizes; (void)n_in; (void)out_size; (void)d_ws; (void)ws_size;
    const int*   net       = (const int*)d_in[0];
    // d_in[1] = reward, unused in forward
    const float* emb_start = (const float*)d_in[2];
    const float* emb_keys  = (const float*)d_in[3];
    const float* fc_W      = (const float*)d_in[4];
    const float* fc_b      = (const float*)d_in[5];
    const float* W_ih      = (const float*)d_in[6];
    const float* W_hh      = (const float*)d_in[7];
    const float* b_ih      = (const float*)d_in[8];
    const float* b_hh      = (const float*)d_in[9];
    float*       out       = (float*)d_out;

    hipLaunchKernelGGL(nas_policy_kernel, dim3(1), dim3(1024), 0, stream,
                       net, emb_start, emb_keys, fc_W, fc_b,
                       W_ih, W_hh, b_ih, b_hh, out);
}